// Round 2
// baseline (100.349 us; speedup 1.0000x reference)
//
#include <hip/hip_runtime.h>
#include <stdint.h>
#include <math.h>

#define THREADS 1024
#define NBINS 8192
#define BIN_SHIFT 19
#define CAND_MAX 2048
#define MAXK 64
#define BATCH 16

// order-preserving fp32 -> uint32 key
__device__ __forceinline__ uint32_t fkey(float f) {
    uint32_t b = __float_as_uint(f);
    return (b & 0x80000000u) ? ~b : (b | 0x80000000u);
}
__device__ __forceinline__ float fval(uint32_t k) {
    uint32_t b = (k & 0x80000000u) ? (k & 0x7FFFFFFFu) : ~k;
    return __uint_as_float(b);
}

__global__ __launch_bounds__(THREADS) void sampler_kernel(
    const float* __restrict__ logits,
    const float* __restrict__ temperature,
    const float* __restrict__ top_p,
    const int* __restrict__ token_lengths,
    const int* __restrict__ top_k_ptr,
    int* __restrict__ out, int V)
{
    const int row = blockIdx.x;
    const int tid = threadIdx.x;
    int K = *top_k_ptr;
    if (K < 1) K = 1;
    if (K > MAXK) K = MAXK;

    __shared__ uint32_t s_hist[NBINS];
    __shared__ uint32_t s_chunk[THREADS];
    __shared__ unsigned long long s_cand[CAND_MAX];
    __shared__ unsigned long long s_top[MAXK];
    __shared__ float s_vals[MAXK];
    __shared__ int s_idx[MAXK];
    __shared__ int s_slot[MAXK];
    __shared__ int s_T, s_cnt;

    // ---------- phase 1: histogram over ordered-key top 13 bits ----------
    for (int i = tid; i < NBINS; i += THREADS) s_hist[i] = 0u;
    if (tid == 0) s_cnt = 0;
    __syncthreads();

    const float* rowbase = logits + (size_t)row * (size_t)V;
    const int nv = V >> 2;                       // float4 count (V expected %4==0)
    const float4* rowp = reinterpret_cast<const float4*>(rowbase);
    // sentinel with fkey()==0 (bin 0): uint 0xFFFFFFFF
    const float SENT = __uint_as_float(0xFFFFFFFFu);
    const float4 SENT4 = make_float4(SENT, SENT, SENT, SENT);

    // batched streaming: 16 float4 loads in flight per thread, then LDS atomics
    for (int base = tid; base < nv; base += THREADS * BATCH) {
        float4 x[BATCH];
        #pragma unroll
        for (int b = 0; b < BATCH; ++b) {
            const int j = base + b * THREADS;
            x[b] = (j < nv) ? rowp[j] : SENT4;
        }
        #pragma unroll
        for (int b = 0; b < BATCH; ++b) {
            atomicAdd(&s_hist[fkey(x[b].x) >> BIN_SHIFT], 1u);
            atomicAdd(&s_hist[fkey(x[b].y) >> BIN_SHIFT], 1u);
            atomicAdd(&s_hist[fkey(x[b].z) >> BIN_SHIFT], 1u);
            atomicAdd(&s_hist[fkey(x[b].w) >> BIN_SHIFT], 1u);
        }
    }
    __syncthreads();

    // ---------- phase 2: threshold bin T (count of bins >= T is >= K) ----------
    const int CHUNK = NBINS / THREADS;  // 8
    {
        uint32_t cs = 0;
        const int base = tid * CHUNK;
        #pragma unroll
        for (int b = 0; b < CHUNK; ++b) cs += s_hist[base + b];
        s_chunk[tid] = cs;
    }
    __syncthreads();
    for (int off = 1; off < THREADS; off <<= 1) {
        uint32_t v = (tid + off < THREADS) ? s_chunk[tid + off] : 0u;
        __syncthreads();
        s_chunk[tid] += v;
        __syncthreads();
    }
    {
        uint32_t suf  = s_chunk[tid];
        uint32_t sufn = (tid + 1 < THREADS) ? s_chunk[tid + 1] : 0u;
        if (suf >= (uint32_t)K && sufn < (uint32_t)K) {
            uint32_t acc = sufn;
            int T = tid * CHUNK;
            for (int b = tid * CHUNK + CHUNK - 1; b >= tid * CHUNK; --b) {
                acc += s_hist[b];
                if (acc >= (uint32_t)K) { T = b; break; }
            }
            s_T = T;
        }
    }
    __syncthreads();

    // ---------- phase 3: collect candidates with bin >= T (reads hit L3) ----------
    const uint32_t T = (uint32_t)s_T;
    for (int base = tid; base < nv; base += THREADS * BATCH) {
        float4 x[BATCH];
        #pragma unroll
        for (int b = 0; b < BATCH; ++b) {
            const int j = base + b * THREADS;
            x[b] = (j < nv) ? rowp[j] : SENT4;
        }
        #pragma unroll
        for (int b = 0; b < BATCH; ++b) {
            const uint32_t j4 = (uint32_t)((base + b * THREADS) << 2);
            uint32_t k;
            k = fkey(x[b].x); if ((k >> BIN_SHIFT) >= T) { int p = atomicAdd(&s_cnt, 1); if (p < CAND_MAX) s_cand[p] = ((unsigned long long)k << 32) | (uint32_t)~(j4 + 0u); }
            k = fkey(x[b].y); if ((k >> BIN_SHIFT) >= T) { int p = atomicAdd(&s_cnt, 1); if (p < CAND_MAX) s_cand[p] = ((unsigned long long)k << 32) | (uint32_t)~(j4 + 1u); }
            k = fkey(x[b].z); if ((k >> BIN_SHIFT) >= T) { int p = atomicAdd(&s_cnt, 1); if (p < CAND_MAX) s_cand[p] = ((unsigned long long)k << 32) | (uint32_t)~(j4 + 2u); }
            k = fkey(x[b].w); if ((k >> BIN_SHIFT) >= T) { int p = atomicAdd(&s_cnt, 1); if (p < CAND_MAX) s_cand[p] = ((unsigned long long)k << 32) | (uint32_t)~(j4 + 3u); }
        }
    }
    __syncthreads();

    // ---------- phase 4+: single wave does selection + sampler math ----------
    if (tid >= 64) return;          // no __syncthreads below this point
    const int M = min(s_cnt, CAND_MAX);

    // top-K selection: K rounds of wave max-reduce (value desc, index asc tie-break)
    for (int t = 0; t < K; ++t) {
        unsigned long long best = 0ull;
        for (int j = tid; j < M; j += 64) { unsigned long long u = s_cand[j]; if (u > best) best = u; }
        #pragma unroll
        for (int off = 1; off < 64; off <<= 1) {
            uint32_t lo = (uint32_t)best, hi = (uint32_t)(best >> 32);
            lo = (uint32_t)__shfl_xor((int)lo, off, 64);
            hi = (uint32_t)__shfl_xor((int)hi, off, 64);
            unsigned long long o = ((unsigned long long)hi << 32) | lo;
            if (o > best) best = o;
        }
        for (int j = tid; j < M; j += 64) if (s_cand[j] == best) s_cand[j] = 0ull;
        if (tid == 0) s_top[t] = best;
        __builtin_amdgcn_wave_barrier();
    }

    if (tid < K) {
        unsigned long long u = s_top[tid];
        s_idx[tid]  = (int)(~(uint32_t)u);
        s_vals[tid] = fval((uint32_t)(u >> 32));
    }
    __builtin_amdgcn_wave_barrier();

    const float temp = temperature[row];
    const float tp   = top_p[row];

    // ----- stage 1 softmax over K scaled values (lane i owns slot i) -----
    const float a0 = s_vals[0] / temp;
    float e = 0.f;
    int myidx = -1;
    if (tid < K) {
        myidx = s_idx[tid];
        e = expf(s_vals[tid] / temp - a0);
    }
    float sum = e;
    #pragma unroll
    for (int off = 1; off < 64; off <<= 1) sum += __shfl_xor(sum, off, 64);
    const float p1 = e / sum;

    // suffix-inclusive cumsum: cs_i = sum_{j>=i} p1_j
    float cs = p1;
    #pragma unroll
    for (int off = 1; off < 64; off <<= 1) {
        float o = __shfl_down(cs, off, 64);
        cs += (tid + off < 64) ? o : 0.f;
    }
    const float lim = 1.0f - tp;
    const bool keep = (tid < K) && (tid == 0 || cs > lim);
    const int S = __popcll(__ballot(keep));   // survivors = descending prefix [0,S)

    // ----- stage 2 re-softmax over survivors -----
    float e2 = (tid < S) ? e : 0.f;
    float sum2 = e2;
    #pragma unroll
    for (int off = 1; off < 64; off <<= 1) sum2 += __shfl_xor(sum2, off, 64);
    const float p2 = e2 / sum2;

    // EOS rule
    const bool is_eos = (tid < S) && (myidx == 2);
    float eosp = is_eos ? p2 : 0.f;
    #pragma unroll
    for (int off = 1; off < 64; off <<= 1) eosp += __shfl_xor(eosp, off, 64);
    const bool has_eos = (__ballot(is_eos) != 0ull);
    const float eth = fmaxf(eosp / 100.0f, 0.005f);

    // ----- slot indices: survivors keep their token idx; padding = smallest absent ints -----
    if (tid < S) s_slot[tid] = myidx;
    __builtin_amdgcn_wave_barrier();
    if (tid == 0) {
        unsigned long long m0 = 0ull, m1 = 0ull;
        for (int i = 0; i < S; ++i) {
            int id = s_idx[i];
            if (id < 64) m0 |= 1ull << id;
            else if (id < 128) m1 |= 1ull << (id - 64);
        }
        int nxt = 0;
        for (int i = S; i < K; ++i) {
            while ((nxt < 64) ? ((m0 >> nxt) & 1ull) : ((m1 >> (nxt - 64)) & 1ull)) nxt++;
            s_slot[i] = nxt++;
        }
    }
    __builtin_amdgcn_wave_barrier();

    // ----- length softmax over all K slots -----
    float len = -INFINITY;
    if (tid < K) {
        int id = s_slot[tid];
        id = (id < 0) ? 0 : ((id >= V) ? V - 1 : id);
        len = (float)token_lengths[id];
    }
    float lmax = len;
    #pragma unroll
    for (int off = 1; off < 64; off <<= 1) lmax = fmaxf(lmax, __shfl_xor(lmax, off, 64));
    float el = (tid < K) ? expf(len - lmax) : 0.f;
    float lsum = el;
    #pragma unroll
    for (int off = 1; off < 64; off <<= 1) lsum += __shfl_xor(lsum, off, 64);
    const float ls = el / lsum;

    // ----- mix + masks + first-occurrence argmax -----
    float mix = -INFINITY;
    if (tid < S) {
        mix = 0.5f * p2 + 0.5f * ls;
        if (!(p2 >= 0.001f)) mix = -INFINITY;
        if (has_eos && !(p2 >= eth)) mix = -INFINITY;
    }
    float bm = mix; int bi = tid;
    #pragma unroll
    for (int off = 1; off < 64; off <<= 1) {
        float om = __shfl_xor(bm, off, 64);
        int   oi = __shfl_xor(bi, off, 64);
        if (om > bm || (om == bm && oi < bi)) { bm = om; bi = oi; }
    }

    if (tid == 0) {
        int chosen = s_slot[bi];
        if (temp < 1e-5f) chosen = s_idx[0];   // greedy branch
        out[row] = chosen;
    }
}

extern "C" void kernel_launch(void* const* d_in, const int* in_sizes, int n_in,
                              void* d_out, int out_size, void* d_ws, size_t ws_size,
                              hipStream_t stream) {
    const float* logits        = (const float*)d_in[0];
    const float* temperature   = (const float*)d_in[1];
    const float* top_p         = (const float*)d_in[2];
    const int*   token_lengths = (const int*)d_in[3];
    const int*   top_k_ptr     = (const int*)d_in[4];
    int* outp = (int*)d_out;

    const int B = in_sizes[1];   // temperature length
    const int V = in_sizes[3];   // token_lengths length

    sampler_kernel<<<B, THREADS, 0, stream>>>(logits, temperature, top_p,
                                              token_lengths, top_k_ptr, outp, V);
}

// Round 3
// 84.796 us; speedup vs baseline: 1.1834x; 1.1834x over previous
//
#include <hip/hip_runtime.h>
#include <stdint.h>
#include <math.h>

#define THREADS 1024
#define NBINS 8192
#define BIN_SHIFT 19
#define CAND_MAX 2048
#define MAXK 64
#define BATCH 16

// order-preserving fp32 -> uint32 key
__device__ __forceinline__ uint32_t fkey(float f) {
    uint32_t b = __float_as_uint(f);
    return (b & 0x80000000u) ? ~b : (b | 0x80000000u);
}
__device__ __forceinline__ float fval(uint32_t k) {
    uint32_t b = (k & 0x80000000u) ? (k & 0x7FFFFFFFu) : ~k;
    return __uint_as_float(b);
}

__global__ __launch_bounds__(THREADS, 1) void sampler_kernel(
    const float* __restrict__ logits,
    const float* __restrict__ temperature,
    const float* __restrict__ top_p,
    const int* __restrict__ token_lengths,
    const int* __restrict__ top_k_ptr,
    int* __restrict__ out, int V)
{
    const int row = blockIdx.x;
    const int tid = threadIdx.x;
    int K = *top_k_ptr;
    if (K < 1) K = 1;
    if (K > MAXK) K = MAXK;

    __shared__ uint32_t s_hist[NBINS];
    __shared__ uint32_t s_chunk[THREADS];
    __shared__ unsigned long long s_cand[CAND_MAX];
    __shared__ unsigned long long s_top[MAXK];
    __shared__ float s_vals[MAXK];
    __shared__ int s_idx[MAXK];
    __shared__ int s_slot[MAXK];
    __shared__ int s_T, s_cnt;

    // ---------- phase 1: histogram over ordered-key top 13 bits ----------
    for (int i = tid; i < NBINS; i += THREADS) s_hist[i] = 0u;
    if (tid == 0) s_cnt = 0;
    __syncthreads();

    const float* rowbase = logits + (size_t)row * (size_t)V;
    const int nv = V >> 2;                       // float4 count (V expected %4==0)
    const float4* rowp = reinterpret_cast<const float4*>(rowbase);
    const int jmax = nv - 1;

    // batched streaming: 16 UNCONDITIONAL float4 loads in flight per thread
    // (index clamped in-bounds; out-of-range lanes skip the atomic instead)
    for (int base = tid; base < nv; base += THREADS * BATCH) {
        float4 x[BATCH];
        #pragma unroll
        for (int b = 0; b < BATCH; ++b) {
            int j = base + b * THREADS;
            x[b] = rowp[(j < jmax) ? j : jmax];
        }
        #pragma unroll
        for (int b = 0; b < BATCH; ++b) {
            const int j = base + b * THREADS;
            if (j < nv) {
                atomicAdd(&s_hist[fkey(x[b].x) >> BIN_SHIFT], 1u);
                atomicAdd(&s_hist[fkey(x[b].y) >> BIN_SHIFT], 1u);
                atomicAdd(&s_hist[fkey(x[b].z) >> BIN_SHIFT], 1u);
                atomicAdd(&s_hist[fkey(x[b].w) >> BIN_SHIFT], 1u);
            }
        }
    }
    __syncthreads();

    // ---------- phase 2: threshold bin T (count of bins >= T is >= K) ----------
    const int CHUNK = NBINS / THREADS;  // 8
    {
        uint32_t cs = 0;
        const int base = tid * CHUNK;
        #pragma unroll
        for (int b = 0; b < CHUNK; ++b) cs += s_hist[base + b];
        s_chunk[tid] = cs;
    }
    __syncthreads();
    for (int off = 1; off < THREADS; off <<= 1) {
        uint32_t v = (tid + off < THREADS) ? s_chunk[tid + off] : 0u;
        __syncthreads();
        s_chunk[tid] += v;
        __syncthreads();
    }
    {
        uint32_t suf  = s_chunk[tid];
        uint32_t sufn = (tid + 1 < THREADS) ? s_chunk[tid + 1] : 0u;
        if (suf >= (uint32_t)K && sufn < (uint32_t)K) {
            uint32_t acc = sufn;
            int T = tid * CHUNK;
            for (int b = tid * CHUNK + CHUNK - 1; b >= tid * CHUNK; --b) {
                acc += s_hist[b];
                if (acc >= (uint32_t)K) { T = b; break; }
            }
            s_T = T;
        }
    }
    __syncthreads();

    // ---------- phase 3: collect candidates with bin >= T (reads hit L3) ----------
    const uint32_t T = (uint32_t)s_T;
    for (int base = tid; base < nv; base += THREADS * BATCH) {
        float4 x[BATCH];
        #pragma unroll
        for (int b = 0; b < BATCH; ++b) {
            int j = base + b * THREADS;
            x[b] = rowp[(j < jmax) ? j : jmax];
        }
        #pragma unroll
        for (int b = 0; b < BATCH; ++b) {
            const int j = base + b * THREADS;
            if (j < nv) {
                const uint32_t j4 = (uint32_t)(j << 2);
                uint32_t k;
                k = fkey(x[b].x); if ((k >> BIN_SHIFT) >= T) { int p = atomicAdd(&s_cnt, 1); if (p < CAND_MAX) s_cand[p] = ((unsigned long long)k << 32) | (uint32_t)~(j4 + 0u); }
                k = fkey(x[b].y); if ((k >> BIN_SHIFT) >= T) { int p = atomicAdd(&s_cnt, 1); if (p < CAND_MAX) s_cand[p] = ((unsigned long long)k << 32) | (uint32_t)~(j4 + 1u); }
                k = fkey(x[b].z); if ((k >> BIN_SHIFT) >= T) { int p = atomicAdd(&s_cnt, 1); if (p < CAND_MAX) s_cand[p] = ((unsigned long long)k << 32) | (uint32_t)~(j4 + 2u); }
                k = fkey(x[b].w); if ((k >> BIN_SHIFT) >= T) { int p = atomicAdd(&s_cnt, 1); if (p < CAND_MAX) s_cand[p] = ((unsigned long long)k << 32) | (uint32_t)~(j4 + 3u); }
            }
        }
    }
    __syncthreads();

    // ---------- phase 4+: single wave does selection + sampler math ----------
    if (tid >= 64) return;          // no __syncthreads below this point
    const int M = min(s_cnt, CAND_MAX);

    // top-K selection: K rounds of wave max-reduce (value desc, index asc tie-break)
    for (int t = 0; t < K; ++t) {
        unsigned long long best = 0ull;
        for (int j = tid; j < M; j += 64) { unsigned long long u = s_cand[j]; if (u > best) best = u; }
        #pragma unroll
        for (int off = 1; off < 64; off <<= 1) {
            uint32_t lo = (uint32_t)best, hi = (uint32_t)(best >> 32);
            lo = (uint32_t)__shfl_xor((int)lo, off, 64);
            hi = (uint32_t)__shfl_xor((int)hi, off, 64);
            unsigned long long o = ((unsigned long long)hi << 32) | lo;
            if (o > best) best = o;
        }
        for (int j = tid; j < M; j += 64) if (s_cand[j] == best) s_cand[j] = 0ull;
        if (tid == 0) s_top[t] = best;
        __builtin_amdgcn_wave_barrier();
    }

    if (tid < K) {
        unsigned long long u = s_top[tid];
        s_idx[tid]  = (int)(~(uint32_t)u);
        s_vals[tid] = fval((uint32_t)(u >> 32));
    }
    __builtin_amdgcn_wave_barrier();

    const float temp = temperature[row];
    const float tp   = top_p[row];

    // ----- stage 1 softmax over K scaled values (lane i owns slot i) -----
    const float a0 = s_vals[0] / temp;
    float e = 0.f;
    int myidx = -1;
    if (tid < K) {
        myidx = s_idx[tid];
        e = expf(s_vals[tid] / temp - a0);
    }
    float sum = e;
    #pragma unroll
    for (int off = 1; off < 64; off <<= 1) sum += __shfl_xor(sum, off, 64);
    const float p1 = e / sum;

    // suffix-inclusive cumsum: cs_i = sum_{j>=i} p1_j
    float cs = p1;
    #pragma unroll
    for (int off = 1; off < 64; off <<= 1) {
        float o = __shfl_down(cs, off, 64);
        cs += (tid + off < 64) ? o : 0.f;
    }
    const float lim = 1.0f - tp;
    const bool keep = (tid < K) && (tid == 0 || cs > lim);
    const int S = __popcll(__ballot(keep));   // survivors = descending prefix [0,S)

    // ----- stage 2 re-softmax over survivors -----
    float e2 = (tid < S) ? e : 0.f;
    float sum2 = e2;
    #pragma unroll
    for (int off = 1; off < 64; off <<= 1) sum2 += __shfl_xor(sum2, off, 64);
    const float p2 = e2 / sum2;

    // EOS rule
    const bool is_eos = (tid < S) && (myidx == 2);
    float eosp = is_eos ? p2 : 0.f;
    #pragma unroll
    for (int off = 1; off < 64; off <<= 1) eosp += __shfl_xor(eosp, off, 64);
    const bool has_eos = (__ballot(is_eos) != 0ull);
    const float eth = fmaxf(eosp / 100.0f, 0.005f);

    // ----- slot indices: survivors keep their token idx; padding = smallest absent ints -----
    if (tid < S) s_slot[tid] = myidx;
    __builtin_amdgcn_wave_barrier();
    if (tid == 0) {
        unsigned long long m0 = 0ull, m1 = 0ull;
        for (int i = 0; i < S; ++i) {
            int id = s_idx[i];
            if (id < 64) m0 |= 1ull << id;
            else if (id < 128) m1 |= 1ull << (id - 64);
        }
        int nxt = 0;
        for (int i = S; i < K; ++i) {
            while ((nxt < 64) ? ((m0 >> nxt) & 1ull) : ((m1 >> (nxt - 64)) & 1ull)) nxt++;
            s_slot[i] = nxt++;
        }
    }
    __builtin_amdgcn_wave_barrier();

    // ----- length softmax over all K slots -----
    float len = -INFINITY;
    if (tid < K) {
        int id = s_slot[tid];
        id = (id < 0) ? 0 : ((id >= V) ? V - 1 : id);
        len = (float)token_lengths[id];
    }
    float lmax = len;
    #pragma unroll
    for (int off = 1; off < 64; off <<= 1) lmax = fmaxf(lmax, __shfl_xor(lmax, off, 64));
    float el = (tid < K) ? expf(len - lmax) : 0.f;
    float lsum = el;
    #pragma unroll
    for (int off = 1; off < 64; off <<= 1) lsum += __shfl_xor(lsum, off, 64);
    const float ls = el / lsum;

    // ----- mix + masks + first-occurrence argmax -----
    float mix = -INFINITY;
    if (tid < S) {
        mix = 0.5f * p2 + 0.5f * ls;
        if (!(p2 >= 0.001f)) mix = -INFINITY;
        if (has_eos && !(p2 >= eth)) mix = -INFINITY;
    }
    float bm = mix; int bi = tid;
    #pragma unroll
    for (int off = 1; off < 64; off <<= 1) {
        float om = __shfl_xor(bm, off, 64);
        int   oi = __shfl_xor(bi, off, 64);
        if (om > bm || (om == bm && oi < bi)) { bm = om; bi = oi; }
    }

    if (tid == 0) {
        int chosen = s_slot[bi];
        if (temp < 1e-5f) chosen = s_idx[0];   // greedy branch
        out[row] = chosen;
    }
}

extern "C" void kernel_launch(void* const* d_in, const int* in_sizes, int n_in,
                              void* d_out, int out_size, void* d_ws, size_t ws_size,
                              hipStream_t stream) {
    const float* logits        = (const float*)d_in[0];
    const float* temperature   = (const float*)d_in[1];
    const float* top_p         = (const float*)d_in[2];
    const int*   token_lengths = (const int*)d_in[3];
    const int*   top_k_ptr     = (const int*)d_in[4];
    int* outp = (int*)d_out;

    const int B = in_sizes[1];   // temperature length
    const int V = in_sizes[3];   // token_lengths length

    sampler_kernel<<<B, THREADS, 0, stream>>>(logits, temperature, top_p,
                                              token_lengths, top_k_ptr, outp, V);
}

// Round 4
// 56.245 us; speedup vs baseline: 1.7841x; 1.5076x over previous
//
#include <hip/hip_runtime.h>
#include <stdint.h>
#include <math.h>

#define THREADS 1024
#define NBINS 8192
#define BIN_SHIFT 19
#define CAND_MAX 2048
#define MAXK 64
#define BATCH 16

// order-preserving fp32 -> uint32 key
__device__ __forceinline__ uint32_t fkey(float f) {
    uint32_t b = __float_as_uint(f);
    return (b & 0x80000000u) ? ~b : (b | 0x80000000u);
}
__device__ __forceinline__ float fval(uint32_t k) {
    uint32_t b = (k & 0x80000000u) ? (k & 0x7FFFFFFFu) : ~k;
    return __uint_as_float(b);
}

__global__ __launch_bounds__(THREADS, 1) void sampler_kernel(
    const float* __restrict__ logits,
    const float* __restrict__ temperature,
    const float* __restrict__ top_p,
    const int* __restrict__ token_lengths,
    const int* __restrict__ top_k_ptr,
    int* __restrict__ out, int V)
{
    const int row = blockIdx.x;
    const int tid = threadIdx.x;
    int K = *top_k_ptr;
    if (K < 1) K = 1;
    if (K > MAXK) K = MAXK;

    __shared__ uint32_t s_hist[NBINS];
    __shared__ uint32_t s_chunk[THREADS];
    __shared__ unsigned long long s_cand[CAND_MAX];
    __shared__ float s_vals[MAXK];
    __shared__ int s_idx[MAXK];
    __shared__ int s_slot[MAXK];
    __shared__ int s_T, s_cnt;

    // ---------- phase 1: histogram over ordered-key top 13 bits ----------
    for (int i = tid; i < NBINS; i += THREADS) s_hist[i] = 0u;
    if (tid == 0) s_cnt = 0;
    __syncthreads();

    const float* rowbase = logits + (size_t)row * (size_t)V;
    const int nv = V >> 2;                       // float4 count (V expected %4==0)
    const float4* rowp = reinterpret_cast<const float4*>(rowbase);
    const int jmax = nv - 1;

    // batched streaming: unconditional clamped loads, predicated atomics
    for (int base = tid; base < nv; base += THREADS * BATCH) {
        float4 x[BATCH];
        #pragma unroll
        for (int b = 0; b < BATCH; ++b) {
            int j = base + b * THREADS;
            x[b] = rowp[(j < jmax) ? j : jmax];
        }
        #pragma unroll
        for (int b = 0; b < BATCH; ++b) {
            const int j = base + b * THREADS;
            if (j < nv) {
                atomicAdd(&s_hist[fkey(x[b].x) >> BIN_SHIFT], 1u);
                atomicAdd(&s_hist[fkey(x[b].y) >> BIN_SHIFT], 1u);
                atomicAdd(&s_hist[fkey(x[b].z) >> BIN_SHIFT], 1u);
                atomicAdd(&s_hist[fkey(x[b].w) >> BIN_SHIFT], 1u);
            }
        }
    }
    __syncthreads();

    // ---------- phase 2: threshold bin T (count of bins >= T is >= K) ----------
    const int CHUNK = NBINS / THREADS;  // 8
    {
        uint32_t cs = 0;
        const int base = tid * CHUNK;
        #pragma unroll
        for (int b = 0; b < CHUNK; ++b) cs += s_hist[base + b];
        s_chunk[tid] = cs;
    }
    __syncthreads();
    for (int off = 1; off < THREADS; off <<= 1) {
        uint32_t v = (tid + off < THREADS) ? s_chunk[tid + off] : 0u;
        __syncthreads();
        s_chunk[tid] += v;
        __syncthreads();
    }
    {
        uint32_t suf  = s_chunk[tid];
        uint32_t sufn = (tid + 1 < THREADS) ? s_chunk[tid + 1] : 0u;
        if (suf >= (uint32_t)K && sufn < (uint32_t)K) {
            uint32_t acc = sufn;
            int T = tid * CHUNK;
            for (int b = tid * CHUNK + CHUNK - 1; b >= tid * CHUNK; --b) {
                acc += s_hist[b];
                if (acc >= (uint32_t)K) { T = b; break; }
            }
            s_T = T;
        }
    }
    __syncthreads();

    // ---------- phase 3: collect candidates with bin >= T (reads hit L3) ----------
    const uint32_t T = (uint32_t)s_T;
    for (int base = tid; base < nv; base += THREADS * BATCH) {
        float4 x[BATCH];
        #pragma unroll
        for (int b = 0; b < BATCH; ++b) {
            int j = base + b * THREADS;
            x[b] = rowp[(j < jmax) ? j : jmax];
        }
        #pragma unroll
        for (int b = 0; b < BATCH; ++b) {
            const int j = base + b * THREADS;
            if (j < nv) {
                const uint32_t j4 = (uint32_t)(j << 2);
                uint32_t k;
                k = fkey(x[b].x); if ((k >> BIN_SHIFT) >= T) { int p = atomicAdd(&s_cnt, 1); if (p < CAND_MAX) s_cand[p] = ((unsigned long long)k << 32) | (uint32_t)~(j4 + 0u); }
                k = fkey(x[b].y); if ((k >> BIN_SHIFT) >= T) { int p = atomicAdd(&s_cnt, 1); if (p < CAND_MAX) s_cand[p] = ((unsigned long long)k << 32) | (uint32_t)~(j4 + 1u); }
                k = fkey(x[b].z); if ((k >> BIN_SHIFT) >= T) { int p = atomicAdd(&s_cnt, 1); if (p < CAND_MAX) s_cand[p] = ((unsigned long long)k << 32) | (uint32_t)~(j4 + 2u); }
                k = fkey(x[b].w); if ((k >> BIN_SHIFT) >= T) { int p = atomicAdd(&s_cnt, 1); if (p < CAND_MAX) s_cand[p] = ((unsigned long long)k << 32) | (uint32_t)~(j4 + 3u); }
            }
        }
    }
    __syncthreads();

    // ---------- phase 4: PARALLEL rank-based top-K selection ----------
    // Each thread ranks candidate t against all M (packed u64 gives exact
    // total order: value desc, index asc). rank < MAXK -> direct write.
    const int M = min(s_cnt, CAND_MAX);
    for (int t = tid; t < M; t += THREADS) {
        const unsigned long long mine = s_cand[t];
        int rank = 0;
        for (int j = 0; j < M; ++j) rank += (s_cand[j] > mine) ? 1 : 0;
        if (rank < MAXK) {
            s_idx[rank]  = (int)(~(uint32_t)mine);
            s_vals[rank] = fval((uint32_t)(mine >> 32));
        }
    }
    __syncthreads();

    // ---------- phase 5: single wave does the sampler math ----------
    if (tid >= 64) return;          // no __syncthreads below this point

    const float temp = temperature[row];
    const float tp   = top_p[row];

    // ----- stage 1 softmax over K scaled values (lane i owns slot i) -----
    const float a0 = s_vals[0] / temp;
    float e = 0.f;
    int myidx = -1;
    if (tid < K) {
        myidx = s_idx[tid];
        e = expf(s_vals[tid] / temp - a0);
    }
    float sum = e;
    #pragma unroll
    for (int off = 1; off < 64; off <<= 1) sum += __shfl_xor(sum, off, 64);
    const float p1 = e / sum;

    // suffix-inclusive cumsum: cs_i = sum_{j>=i} p1_j
    float cs = p1;
    #pragma unroll
    for (int off = 1; off < 64; off <<= 1) {
        float o = __shfl_down(cs, off, 64);
        cs += (tid + off < 64) ? o : 0.f;
    }
    const float lim = 1.0f - tp;
    const bool keep = (tid < K) && (tid == 0 || cs > lim);
    const int S = __popcll(__ballot(keep));   // survivors = descending prefix [0,S)

    // ----- stage 2 re-softmax over survivors -----
    float e2 = (tid < S) ? e : 0.f;
    float sum2 = e2;
    #pragma unroll
    for (int off = 1; off < 64; off <<= 1) sum2 += __shfl_xor(sum2, off, 64);
    const float p2 = e2 / sum2;

    // EOS rule
    const bool is_eos = (tid < S) && (myidx == 2);
    float eosp = is_eos ? p2 : 0.f;
    #pragma unroll
    for (int off = 1; off < 64; off <<= 1) eosp += __shfl_xor(eosp, off, 64);
    const bool has_eos = (__ballot(is_eos) != 0ull);
    const float eth = fmaxf(eosp / 100.0f, 0.005f);

    // ----- slot indices: survivors keep their token idx; padding = smallest absent ints -----
    if (tid < S) s_slot[tid] = myidx;
    __builtin_amdgcn_wave_barrier();
    if (tid == 0) {
        unsigned long long m0 = 0ull, m1 = 0ull;
        for (int i = 0; i < S; ++i) {
            int id = s_idx[i];
            if (id < 64) m0 |= 1ull << id;
            else if (id < 128) m1 |= 1ull << (id - 64);
        }
        int nxt = 0;
        for (int i = S; i < K; ++i) {
            while ((nxt < 64) ? ((m0 >> nxt) & 1ull) : ((m1 >> (nxt - 64)) & 1ull)) nxt++;
            s_slot[i] = nxt++;
        }
    }
    __builtin_amdgcn_wave_barrier();

    // ----- length softmax over all K slots -----
    float len = -INFINITY;
    if (tid < K) {
        int id = s_slot[tid];
        id = (id < 0) ? 0 : ((id >= V) ? V - 1 : id);
        len = (float)token_lengths[id];
    }
    float lmax = len;
    #pragma unroll
    for (int off = 1; off < 64; off <<= 1) lmax = fmaxf(lmax, __shfl_xor(lmax, off, 64));
    float el = (tid < K) ? expf(len - lmax) : 0.f;
    float lsum = el;
    #pragma unroll
    for (int off = 1; off < 64; off <<= 1) lsum += __shfl_xor(lsum, off, 64);
    const float ls = el / lsum;

    // ----- mix + masks + first-occurrence argmax -----
    float mix = -INFINITY;
    if (tid < S) {
        mix = 0.5f * p2 + 0.5f * ls;
        if (!(p2 >= 0.001f)) mix = -INFINITY;
        if (has_eos && !(p2 >= eth)) mix = -INFINITY;
    }
    float bm = mix; int bi = tid;
    #pragma unroll
    for (int off = 1; off < 64; off <<= 1) {
        float om = __shfl_xor(bm, off, 64);
        int   oi = __shfl_xor(bi, off, 64);
        if (om > bm || (om == bm && oi < bi)) { bm = om; bi = oi; }
    }

    if (tid == 0) {
        int chosen = s_slot[bi];
        if (temp < 1e-5f) chosen = s_idx[0];   // greedy branch
        out[row] = chosen;
    }
}

extern "C" void kernel_launch(void* const* d_in, const int* in_sizes, int n_in,
                              void* d_out, int out_size, void* d_ws, size_t ws_size,
                              hipStream_t stream) {
    const float* logits        = (const float*)d_in[0];
    const float* temperature   = (const float*)d_in[1];
    const float* top_p         = (const float*)d_in[2];
    const int*   token_lengths = (const int*)d_in[3];
    const int*   top_k_ptr     = (const int*)d_in[4];
    int* outp = (int*)d_out;

    const int B = in_sizes[1];   // temperature length
    const int V = in_sizes[3];   // token_lengths length

    sampler_kernel<<<B, THREADS, 0, stream>>>(logits, temperature, top_p,
                                              token_lengths, top_k_ptr, outp, V);
}

// Round 5
// 51.553 us; speedup vs baseline: 1.9465x; 1.0910x over previous
//
#include <hip/hip_runtime.h>
#include <stdint.h>
#include <math.h>

#define THREADS 1024
#define NWAVES 16
#define NBINS 8192
#define BIN_SHIFT 19
#define CAND_MAX 1536
#define MAXK 64
#define RING 4            // LDS slots per wave; RING-1 = 3 chunks in flight

// order-preserving fp32 -> uint32 key
__device__ __forceinline__ uint32_t fkey(float f) {
    uint32_t b = __float_as_uint(f);
    return (b & 0x80000000u) ? ~b : (b | 0x80000000u);
}
__device__ __forceinline__ float fval(uint32_t k) {
    uint32_t b = (k & 0x80000000u) ? (k & 0x7FFFFFFFu) : ~k;
    return __uint_as_float(b);
}

// async global->LDS DMA, 16B per lane; LDS dest = uniform base + lane*16
__device__ __forceinline__ void gload_lds16(const float* g, uint32_t* lds) {
    __builtin_amdgcn_global_load_lds(
        (const __attribute__((address_space(1))) void*)(const void*)g,
        (__attribute__((address_space(3))) void*)(void*)lds,
        16, 0, 0);
}

__global__ __launch_bounds__(THREADS, 1) void sampler_kernel(
    const float* __restrict__ logits,
    const float* __restrict__ temperature,
    const float* __restrict__ top_p,
    const int* __restrict__ token_lengths,
    const int* __restrict__ top_k_ptr,
    int* __restrict__ out, int V)
{
    const int row  = blockIdx.x;
    const int tid  = threadIdx.x;
    const int lane = tid & 63;
    const int wid  = tid >> 6;
    int K = *top_k_ptr;
    if (K < 1) K = 1;
    if (K > MAXK) K = MAXK;

    __shared__ __align__(16) uint32_t s_stage[NWAVES * RING * 256]; // 64 KB
    __shared__ uint32_t s_hist[NBINS];                              // 32 KB
    __shared__ unsigned long long s_cand[CAND_MAX];                 // 12 KB
    __shared__ uint32_t s_wsum[NWAVES], s_wtail[NWAVES];
    __shared__ float s_vals[MAXK];
    __shared__ int s_idx[MAXK], s_slot[MAXK];
    __shared__ int s_T, s_cnt;

    // ---------- init ----------
    for (int i = tid; i < NBINS; i += THREADS) s_hist[i] = 0u;
    if (tid == 0) s_cnt = 0;
    __syncthreads();

    const float* rowbase = logits + (size_t)row * (size_t)V;
    const int NREAL = (V + 255) >> 8;                 // 256-elt (1KB) chunks
    const int NITER = (NREAL + NWAVES - 1) / NWAVES;  // uniform per-wave trips
    const int lastg = V - 4;
    uint32_t* mystage = &s_stage[wid * (RING * 256)];

    // =========== PASS A: histogram, wave-private pipelined stream ===========
    #pragma unroll
    for (int k = 0; k < RING - 1; ++k) {               // prologue: 3 in flight
        int ci = wid + NWAVES * k;
        int c  = (ci < NREAL - 1) ? ci : (NREAL - 1);
        int g  = c * 256 + lane * 4;
        g = (g < lastg) ? g : lastg;
        gload_lds16(rowbase + g, mystage + k * 256);
    }
    for (int i = 0; i < NITER; ++i) {
        asm volatile("s_waitcnt vmcnt(2)" ::: "memory");  // oldest chunk landed
        const uint32_t* sp = mystage + (i & (RING - 1)) * 256 + lane * 4;
        float4 x = *reinterpret_cast<const float4*>(sp);
        const int g0 = (wid + NWAVES * i) * 256 + lane * 4;
        if (g0 < V) {
            atomicAdd(&s_hist[fkey(x.x) >> BIN_SHIFT], 1u);
            atomicAdd(&s_hist[fkey(x.y) >> BIN_SHIFT], 1u);
            atomicAdd(&s_hist[fkey(x.z) >> BIN_SHIFT], 1u);
            atomicAdd(&s_hist[fkey(x.w) >> BIN_SHIFT], 1u);
        }
        {   // issue chunk i+3 into the slot consumed at i+3 (clamped tail)
            int ci = wid + NWAVES * (i + RING - 1);
            int c  = (ci < NREAL - 1) ? ci : (NREAL - 1);
            int g  = c * 256 + lane * 4;
            g = (g < lastg) ? g : lastg;
            gload_lds16(rowbase + g, mystage + ((i + RING - 1) & (RING - 1)) * 256);
        }
    }
    asm volatile("s_waitcnt vmcnt(0)" ::: "memory");
    __syncthreads();

    // =========== PHASE 2: threshold bin T (3 barriers, shfl scans) ===========
    const int CH = NBINS / THREADS;  // 8
    uint32_t cs = 0;
    {
        const int b0 = tid * CH;
        #pragma unroll
        for (int b = 0; b < CH; ++b) cs += s_hist[b0 + b];
    }
    uint32_t suf = cs;                                  // in-wave inclusive suffix
    #pragma unroll
    for (int off = 1; off < 64; off <<= 1) {
        uint32_t o = __shfl_down(suf, off, 64);
        suf += (lane + off < 64) ? o : 0u;
    }
    if (lane == 0) s_wsum[wid] = suf;
    __syncthreads();
    if (wid == 0 && lane < NWAVES) {
        uint32_t t = s_wsum[lane];
        uint32_t s = t;
        #pragma unroll
        for (int off = 1; off < NWAVES; off <<= 1) {
            uint32_t o = __shfl_down(s, off, 64);
            s += (lane + off < NWAVES) ? o : 0u;
        }
        s_wtail[lane] = s - t;                          // strictly-after sum
    }
    __syncthreads();
    {
        uint32_t sufg = suf + s_wtail[wid];             // suffix from chunk tid
        uint32_t sufn = sufg - cs;                      // suffix from tid+1
        if (sufg >= (uint32_t)K && sufn < (uint32_t)K) {
            uint32_t acc = sufn;
            int T = tid * CH;
            for (int b = tid * CH + CH - 1; b >= tid * CH; --b) {
                acc += s_hist[b];
                if (acc >= (uint32_t)K) { T = b; break; }
            }
            s_T = T;
        }
    }
    __syncthreads();

    // =========== PASS B: collect candidates (same pipeline, L3-resident) ===========
    const uint32_t T = (uint32_t)s_T;
    #pragma unroll
    for (int k = 0; k < RING - 1; ++k) {
        int ci = wid + NWAVES * k;
        int c  = (ci < NREAL - 1) ? ci : (NREAL - 1);
        int g  = c * 256 + lane * 4;
        g = (g < lastg) ? g : lastg;
        gload_lds16(rowbase + g, mystage + k * 256);
    }
    for (int i = 0; i < NITER; ++i) {
        asm volatile("s_waitcnt vmcnt(2)" ::: "memory");
        const uint32_t* sp = mystage + (i & (RING - 1)) * 256 + lane * 4;
        float4 x = *reinterpret_cast<const float4*>(sp);
        const int g0 = (wid + NWAVES * i) * 256 + lane * 4;
        if (g0 < V) {
            uint32_t k0;
            k0 = fkey(x.x); if ((k0 >> BIN_SHIFT) >= T) { int p = atomicAdd(&s_cnt, 1); if (p < CAND_MAX) s_cand[p] = ((unsigned long long)k0 << 32) | (uint32_t)~(uint32_t)(g0 + 0); }
            k0 = fkey(x.y); if ((k0 >> BIN_SHIFT) >= T) { int p = atomicAdd(&s_cnt, 1); if (p < CAND_MAX) s_cand[p] = ((unsigned long long)k0 << 32) | (uint32_t)~(uint32_t)(g0 + 1); }
            k0 = fkey(x.z); if ((k0 >> BIN_SHIFT) >= T) { int p = atomicAdd(&s_cnt, 1); if (p < CAND_MAX) s_cand[p] = ((unsigned long long)k0 << 32) | (uint32_t)~(uint32_t)(g0 + 2); }
            k0 = fkey(x.w); if ((k0 >> BIN_SHIFT) >= T) { int p = atomicAdd(&s_cnt, 1); if (p < CAND_MAX) s_cand[p] = ((unsigned long long)k0 << 32) | (uint32_t)~(uint32_t)(g0 + 3); }
        }
        {
            int ci = wid + NWAVES * (i + RING - 1);
            int c  = (ci < NREAL - 1) ? ci : (NREAL - 1);
            int g  = c * 256 + lane * 4;
            g = (g < lastg) ? g : lastg;
            gload_lds16(rowbase + g, mystage + ((i + RING - 1) & (RING - 1)) * 256);
        }
    }
    asm volatile("s_waitcnt vmcnt(0)" ::: "memory");
    __syncthreads();

    // =========== PHASE 4: parallel rank-based top-K selection ===========
    const int M = (s_cnt < CAND_MAX) ? s_cnt : CAND_MAX;
    for (int t = tid; t < M; t += THREADS) {
        const unsigned long long mine = s_cand[t];
        int rank = 0;
        for (int j = 0; j < M; ++j) rank += (s_cand[j] > mine) ? 1 : 0;
        if (rank < MAXK) {
            s_idx[rank]  = (int)(~(uint32_t)mine);
            s_vals[rank] = fval((uint32_t)(mine >> 32));
        }
    }
    __syncthreads();

    // =========== PHASE 5: single wave does the sampler math ===========
    if (tid >= 64) return;          // no __syncthreads below this point

    const float temp = temperature[row];
    const float tp   = top_p[row];

    // stage 1 softmax over K scaled values (lane i owns slot i)
    const float a0 = s_vals[0] / temp;
    float e = 0.f;
    int myidx = -1;
    if (tid < K) {
        myidx = s_idx[tid];
        e = expf(s_vals[tid] / temp - a0);
    }
    float sum = e;
    #pragma unroll
    for (int off = 1; off < 64; off <<= 1) sum += __shfl_xor(sum, off, 64);
    const float p1 = e / sum;

    // suffix-inclusive cumsum: cs_i = sum_{j>=i} p1_j
    float csf = p1;
    #pragma unroll
    for (int off = 1; off < 64; off <<= 1) {
        float o = __shfl_down(csf, off, 64);
        csf += (tid + off < 64) ? o : 0.f;
    }
    const float lim = 1.0f - tp;
    const bool keep = (tid < K) && (tid == 0 || csf > lim);
    const int S = __popcll(__ballot(keep));   // survivors = descending prefix [0,S)

    // stage 2 re-softmax over survivors
    float e2 = (tid < S) ? e : 0.f;
    float sum2 = e2;
    #pragma unroll
    for (int off = 1; off < 64; off <<= 1) sum2 += __shfl_xor(sum2, off, 64);
    const float p2 = e2 / sum2;

    // EOS rule
    const bool is_eos = (tid < S) && (myidx == 2);
    float eosp = is_eos ? p2 : 0.f;
    #pragma unroll
    for (int off = 1; off < 64; off <<= 1) eosp += __shfl_xor(eosp, off, 64);
    const bool has_eos = (__ballot(is_eos) != 0ull);
    const float eth = fmaxf(eosp / 100.0f, 0.005f);

    // slot indices: survivors keep token idx; padding = smallest absent ints
    if (tid < S) s_slot[tid] = myidx;
    __builtin_amdgcn_wave_barrier();
    if (tid == 0) {
        unsigned long long m0 = 0ull, m1 = 0ull;
        for (int i = 0; i < S; ++i) {
            int id = s_idx[i];
            if (id < 64) m0 |= 1ull << id;
            else if (id < 128) m1 |= 1ull << (id - 64);
        }
        int nxt = 0;
        for (int i = S; i < K; ++i) {
            while ((nxt < 64) ? ((m0 >> nxt) & 1ull) : ((m1 >> (nxt - 64)) & 1ull)) nxt++;
            s_slot[i] = nxt++;
        }
    }
    __builtin_amdgcn_wave_barrier();

    // length softmax over all K slots
    float len = -INFINITY;
    if (tid < K) {
        int id = s_slot[tid];
        id = (id < 0) ? 0 : ((id >= V) ? V - 1 : id);
        len = (float)token_lengths[id];
    }
    float lmax = len;
    #pragma unroll
    for (int off = 1; off < 64; off <<= 1) lmax = fmaxf(lmax, __shfl_xor(lmax, off, 64));
    float el = (tid < K) ? expf(len - lmax) : 0.f;
    float lsum = el;
    #pragma unroll
    for (int off = 1; off < 64; off <<= 1) lsum += __shfl_xor(lsum, off, 64);
    const float ls = el / lsum;

    // mix + masks + first-occurrence argmax
    float mix = -INFINITY;
    if (tid < S) {
        mix = 0.5f * p2 + 0.5f * ls;
        if (!(p2 >= 0.001f)) mix = -INFINITY;
        if (has_eos && !(p2 >= eth)) mix = -INFINITY;
    }
    float bm = mix; int bi = tid;
    #pragma unroll
    for (int off = 1; off < 64; off <<= 1) {
        float om = __shfl_xor(bm, off, 64);
        int   oi = __shfl_xor(bi, off, 64);
        if (om > bm || (om == bm && oi < bi)) { bm = om; bi = oi; }
    }

    if (tid == 0) {
        int chosen = s_slot[bi];
        if (temp < 1e-5f) chosen = s_idx[0];   // greedy branch
        out[row] = chosen;
    }
}

extern "C" void kernel_launch(void* const* d_in, const int* in_sizes, int n_in,
                              void* d_out, int out_size, void* d_ws, size_t ws_size,
                              hipStream_t stream) {
    const float* logits        = (const float*)d_in[0];
    const float* temperature   = (const float*)d_in[1];
    const float* top_p         = (const float*)d_in[2];
    const int*   token_lengths = (const int*)d_in[3];
    const int*   top_k_ptr     = (const int*)d_in[4];
    int* outp = (int*)d_out;

    const int B = in_sizes[1];   // temperature length
    const int V = in_sizes[3];   // token_lengths length

    sampler_kernel<<<B, THREADS, 0, stream>>>(logits, temperature, top_p,
                                              token_lengths, top_k_ptr, outp, V);
}